// Round 4
// baseline (749.750 us; speedup 1.0000x reference)
//
#include <hip/hip_runtime.h>

#define EPS 1e-6f
#define V_LO 0.95f
#define V_HI 1.05f
#define NXCD 8
#define CHUNK 1024          // edges per queue grab (4 iters of 256 threads)
#define OWNER(n) (((unsigned)(n) >> 11) & (NXCD - 1))  // 2048-node blocks, 128B-line aligned

// Physical XCD id of the CU this wave runs on (verified gfx950, learn_hip m09).
__device__ __forceinline__ int xcc_id() {
    int x;
    asm volatile("s_getreg_b32 %0, hwreg(HW_REG_XCC_ID)" : "=s"(x));
    return x & (NXCD - 1);
}

// Workgroup-scope relaxed fadd: should emit global_atomic_add_f32 WITHOUT sc1
// -> RMW executes in the local XCD's L2. Correct here because every writer of
// a given flow cache line is pinned to the owning XCD.
__device__ __forceinline__ void l2_atomic_add(float* addr, float v) {
    __hip_atomic_fetch_add(addr, v, __ATOMIC_RELAXED, __HIP_MEMORY_SCOPE_WORKGROUP);
}

// ---------------------------------------------------------------------------
// Kernel 1: each XCD scans all edges via its own dynamic chunk queue and
// commits only the edge-ends whose node it owns.
// ---------------------------------------------------------------------------
__global__ void pf_edge_kernel(const float* __restrict__ nf,
                               const int* __restrict__ ei,        // (2,E)
                               const float* __restrict__ probs,
                               const float2* __restrict__ params, // (E,2)
                               float2* __restrict__ flow,
                               int* __restrict__ queue,           // NXCD counters
                               int n_edges) {
    int myxcd = xcc_id();
    __shared__ int c_sh;
    for (;;) {
        if (threadIdx.x == 0)
            c_sh = atomicAdd(&queue[myxcd], 1);   // device-scope, rare
        __syncthreads();
        int base = c_sh * CHUNK;
        __syncthreads();
        if (base >= n_edges) break;

        #pragma unroll
        for (int i = 0; i < CHUNK; i += 256) {
            int e = base + i + threadIdx.x;
            if (e >= n_edges) continue;
            int src = ei[e];
            int dst = ei[n_edges + e];
            bool cs = (OWNER(src) == (unsigned)myxcd);
            bool cd = (OWNER(dst) == (unsigned)myxcd) && (src != dst);
            if (cs | cd) {
                float2 v   = *reinterpret_cast<const float2*>(&nf[(size_t)src * 4]);
                float2 pr  = params[e];
                float prob = probs[e];
                float v2 = v.x * v.x + v.y * v.y;
                float pe = v2 / (pr.x + EPS) * prob;
                float qe = v2 / (pr.y + EPS) * prob;
                if (cs) {
                    l2_atomic_add(&flow[src].x, pe);
                    l2_atomic_add(&flow[src].y, qe);
                }
                if (cd) {
                    l2_atomic_add(&flow[dst].x, pe);
                    l2_atomic_add(&flow[dst].y, qe);
                }
            }
        }
    }
}

// ---------------------------------------------------------------------------
// Kernel 2: per-node loss terms; block-reduce; one atomic per block.
// ---------------------------------------------------------------------------
__global__ void pf_node_kernel(const float* __restrict__ nf,
                               const float2* __restrict__ flow,
                               float* __restrict__ acc,
                               int n_nodes) {
    int i = blockIdx.x * blockDim.x + threadIdx.x;
    float c = 0.0f;
    if (i < n_nodes) {
        float4 f = *reinterpret_cast<const float4*>(&nf[(size_t)i * 4]);
        float2 fl = flow[i];
        float p = f.z + fl.x;
        float q = f.w + fl.y;
        float vmag = sqrtf(f.x * f.x + f.y * f.y);
        float lv = fmaxf(V_LO - vmag, 0.0f);
        float uv = fmaxf(vmag - V_HI, 0.0f);
        c = p * p + q * q + lv * lv + uv * uv;
    }
    #pragma unroll
    for (int off = 32; off > 0; off >>= 1)
        c += __shfl_down(c, off);
    __shared__ float wsum[4];
    int lane = threadIdx.x & 63;
    int wid  = threadIdx.x >> 6;
    if (lane == 0) wsum[wid] = c;
    __syncthreads();
    if (threadIdx.x == 0) {
        float s = 0.0f;
        int nw = blockDim.x >> 6;
        for (int w = 0; w < nw; ++w) s += wsum[w];
        atomicAdd(acc, s);
    }
}

__global__ void pf_finalize_kernel(const float* __restrict__ acc,
                                   float* __restrict__ out,
                                   float inv_n) {
    out[0] = acc[0] * inv_n;
}

extern "C" void kernel_launch(void* const* d_in, const int* in_sizes, int n_in,
                              void* d_out, int out_size, void* d_ws, size_t ws_size,
                              hipStream_t stream) {
    const float*  nf     = (const float*)d_in[0];    // (N,4) f32
    const int*    ei     = (const int*)d_in[1];      // (2,E) int
    const float*  probs  = (const float*)d_in[2];    // (E,) f32
    const float2* params = (const float2*)d_in[3];   // (E,2) f32

    int n_nodes = in_sizes[0] / 4;
    int n_edges = in_sizes[2];

    // ws layout: [queue: 8 ints][acc: 1 float][pad to 128B][flow: n_nodes float2]
    int*    queue = (int*)d_ws;
    float*  acc   = (float*)d_ws + NXCD;
    float2* flow  = (float2*)((char*)d_ws + 128);   // 128B-aligned for line privacy

    // zero queue+acc+flow every call (graph replay does not re-poison)
    hipMemsetAsync(d_ws, 0, 128 + (size_t)n_nodes * sizeof(float2), stream);

    pf_edge_kernel<<<2048, 256, 0, stream>>>(nf, ei, probs, params,
                                             flow, queue, n_edges);

    int nblocks = (n_nodes + 255) / 256;
    pf_node_kernel<<<nblocks, 256, 0, stream>>>(nf, flow, acc, n_nodes);

    pf_finalize_kernel<<<1, 1, 0, stream>>>(acc, (float*)d_out,
                                            1.0f / (float)n_nodes);
}

// Round 5
// 170.059 us; speedup vs baseline: 4.4088x; 4.4088x over previous
//
#include <hip/hip_runtime.h>

#define EPS 1e-6f
#define V_LO 0.95f
#define V_HI 1.05f

#define BIN_BITS 13
#define BIN_SIZE (1 << BIN_BITS)   // 8192 nodes/bin -> float2[8192] = 64 KB LDS
#define TPB 512
#define MAX_SPLIT 39               // 13 bins * 39 slots = 507 blocks ~= 2/CU

// ---------------------------------------------------------------------------
// Edge scan: block (slot, bin) scans edge-chunk `slot`, accumulates ends
// owned by `bin` into LDS (ds_add_f32 atomics), then writes the bin slice to
// partial[slot] with plain stores. NO global atomics in the hot path.
// ---------------------------------------------------------------------------
__global__ __launch_bounds__(TPB) void pf_edge_scan(
    const float* __restrict__ nf,
    const int* __restrict__ ei,        // (2,E): [0..E)=src, [E..2E)=dst
    const float* __restrict__ probs,
    const float2* __restrict__ params, // (E,2)
    float2* __restrict__ partial,      // [split][n_nodes]
    int n_edges, int n_nodes, int nbins, int per_chunk)
{
    int bin  = blockIdx.x % nbins;
    int slot = blockIdx.x / nbins;
    int node_base = bin << BIN_BITS;

    __shared__ float2 lds[BIN_SIZE];   // exactly 64 KB
    for (int i = threadIdx.x; i < BIN_SIZE; i += TPB)
        lds[i] = make_float2(0.0f, 0.0f);
    __syncthreads();

    int e0 = slot * per_chunk;
    int e1 = min(e0 + per_chunk, n_edges);
    for (int e = e0 + threadIdx.x; e < e1; e += TPB) {
        int src = ei[e];
        int dst = ei[n_edges + e];
        bool cs = ((src >> BIN_BITS) == bin);
        bool cd = ((dst >> BIN_BITS) == bin) & (src != dst);
        if (cs | cd) {
            float2 v   = *reinterpret_cast<const float2*>(&nf[(size_t)src * 4]);
            float2 pr  = params[e];
            float prob = probs[e];
            float v2 = v.x * v.x + v.y * v.y;
            float pe = v2 / (pr.x + EPS) * prob;
            float qe = v2 / (pr.y + EPS) * prob;
            if (cs) {
                atomicAdd(&lds[src - node_base].x, pe);   // ds_add_f32
                atomicAdd(&lds[src - node_base].y, qe);
            }
            if (cd) {
                atomicAdd(&lds[dst - node_base].x, pe);
                atomicAdd(&lds[dst - node_base].y, qe);
            }
        }
    }
    __syncthreads();

    int lim = min(BIN_SIZE, n_nodes - node_base);
    float2* out = partial + (size_t)slot * n_nodes + node_base;
    for (int i = threadIdx.x; i < lim; i += TPB)
        out[i] = lds[i];
}

// ---------------------------------------------------------------------------
// Node kernel: sum partials per node, compute loss terms, block-reduce,
// one global atomic per block.
// ---------------------------------------------------------------------------
__global__ void pf_node_kernel(const float* __restrict__ nf,
                               const float2* __restrict__ partial,
                               float* __restrict__ acc,
                               int n_nodes, int split) {
    int i = blockIdx.x * blockDim.x + threadIdx.x;
    float c = 0.0f;
    if (i < n_nodes) {
        float4 f = *reinterpret_cast<const float4*>(&nf[(size_t)i * 4]);
        float p = f.z, q = f.w;
        const float2* pp = partial + i;
        for (int s = 0; s < split; ++s) {
            float2 fl = pp[(size_t)s * n_nodes];
            p += fl.x;
            q += fl.y;
        }
        float vmag = sqrtf(f.x * f.x + f.y * f.y);
        float lv = fmaxf(V_LO - vmag, 0.0f);
        float uv = fmaxf(vmag - V_HI, 0.0f);
        c = p * p + q * q + lv * lv + uv * uv;
    }
    #pragma unroll
    for (int off = 32; off > 0; off >>= 1)
        c += __shfl_down(c, off);
    __shared__ float wsum[4];
    int lane = threadIdx.x & 63;
    int wid  = threadIdx.x >> 6;
    if (lane == 0) wsum[wid] = c;
    __syncthreads();
    if (threadIdx.x == 0) {
        float s = 0.0f;
        int nw = blockDim.x >> 6;
        for (int w = 0; w < nw; ++w) s += wsum[w];
        atomicAdd(acc, s);
    }
}

__global__ void pf_finalize_kernel(const float* __restrict__ acc,
                                   float* __restrict__ out,
                                   float inv_n) {
    out[0] = acc[0] * inv_n;
}

extern "C" void kernel_launch(void* const* d_in, const int* in_sizes, int n_in,
                              void* d_out, int out_size, void* d_ws, size_t ws_size,
                              hipStream_t stream) {
    const float*  nf     = (const float*)d_in[0];    // (N,4) f32
    const int*    ei     = (const int*)d_in[1];      // (2,E) int
    const float*  probs  = (const float*)d_in[2];    // (E,) f32
    const float2* params = (const float2*)d_in[3];   // (E,2) f32

    int n_nodes = in_sizes[0] / 4;
    int n_edges = in_sizes[2];

    // ws layout: [acc (pad to 256B)][partial: split * n_nodes * float2]
    float*  acc     = (float*)d_ws;
    float2* partial = (float2*)((char*)d_ws + 256);

    size_t slot_bytes = (size_t)n_nodes * sizeof(float2);
    int split = (int)((ws_size - 256) / slot_bytes);
    if (split > MAX_SPLIT) split = MAX_SPLIT;
    if (split < 1) split = 1;   // round-1 evidence: ws_size >= 800 KB, so >=1 fits

    int nbins = (n_nodes + BIN_SIZE - 1) >> BIN_BITS;
    int per_chunk = (n_edges + split - 1) / split;

    // only acc needs zeroing: partials are fully overwritten by the scan blocks
    hipMemsetAsync(d_ws, 0, 256, stream);

    pf_edge_scan<<<nbins * split, TPB, 0, stream>>>(nf, ei, probs, params,
                                                    partial, n_edges, n_nodes,
                                                    nbins, per_chunk);

    int nblocks = (n_nodes + 255) / 256;
    pf_node_kernel<<<nblocks, 256, 0, stream>>>(nf, partial, acc, n_nodes, split);

    pf_finalize_kernel<<<1, 1, 0, stream>>>(acc, (float*)d_out,
                                            1.0f / (float)n_nodes);
}

// Round 6
// 112.253 us; speedup vs baseline: 6.6791x; 1.5150x over previous
//
#include <hip/hip_runtime.h>

#define EPS 1e-6f
#define V_LO 0.95f
#define V_HI 1.05f

#define BIN_ELEMS 20480            // float2[20480] = 160 KB LDS (full CU)
#define TPB 1024                   // 16 waves, 1 block/CU
#define MAX_SPLIT 51               // 5 bins * 51 slots = 255 blocks

// ---------------------------------------------------------------------------
// Edge scan: block (slot, bin) scans edge-chunk `slot` (2 edges/thread,
// vectorized loads), accumulates ends in bin's node range into LDS
// (ds_add_f32), then writes the bin slice to partial[slot] with plain stores.
// No global atomics in the hot path.
// ---------------------------------------------------------------------------
__global__ __launch_bounds__(TPB) void pf_edge_scan(
    const float* __restrict__ nf,
    const int* __restrict__ ei,        // (2,E): [0..E)=src, [E..2E)=dst
    const float* __restrict__ probs,
    const float* __restrict__ params,  // (E,2) flat
    float2* __restrict__ partial,      // [split][n_nodes]
    int n_edges, int n_nodes, int nbins, int per_chunk)
{
    extern __shared__ float2 lds[];    // BIN_ELEMS entries
    int bin  = blockIdx.x % nbins;
    int slot = blockIdx.x / nbins;
    int node_base = bin * BIN_ELEMS;

    for (int i = threadIdx.x; i < BIN_ELEMS; i += TPB)
        lds[i] = make_float2(0.0f, 0.0f);
    __syncthreads();

    int e0 = slot * per_chunk;                    // per_chunk is even
    int e1 = min(e0 + per_chunk, n_edges);        // n_edges even -> e1 even

    for (int e = e0 + threadIdx.x * 2; e < e1; e += TPB * 2) {
        int2   s2  = *reinterpret_cast<const int2*>(&ei[e]);
        int2   d2  = *reinterpret_cast<const int2*>(&ei[n_edges + e]);
        float2 pb2 = *reinterpret_cast<const float2*>(&probs[e]);
        float4 pr2 = *reinterpret_cast<const float4*>(&params[(size_t)e * 2]);

        #pragma unroll
        for (int k = 0; k < 2; ++k) {
            int   src  = k ? s2.y : s2.x;
            int   dst  = k ? d2.y : d2.x;
            float prob = k ? pb2.y : pb2.x;
            float prx  = k ? pr2.z : pr2.x;
            float pry  = k ? pr2.w : pr2.y;

            unsigned ls = (unsigned)(src - node_base);
            unsigned ld = (unsigned)(dst - node_base);
            bool cs = ls < (unsigned)BIN_ELEMS;
            bool cd = (ld < (unsigned)BIN_ELEMS) & (src != dst);
            if (cs | cd) {
                float2 v = *reinterpret_cast<const float2*>(&nf[(size_t)src * 4]);
                float v2 = v.x * v.x + v.y * v.y;
                float pe = v2 / (prx + EPS) * prob;
                float qe = v2 / (pry + EPS) * prob;
                if (cs) {
                    atomicAdd(&lds[ls].x, pe);    // ds_add_f32
                    atomicAdd(&lds[ls].y, qe);
                }
                if (cd) {
                    atomicAdd(&lds[ld].x, pe);
                    atomicAdd(&lds[ld].y, qe);
                }
            }
        }
    }
    __syncthreads();

    int lim = min(BIN_ELEMS, n_nodes - node_base);
    float2* out = partial + (size_t)slot * n_nodes + node_base;
    for (int i = threadIdx.x; i < lim; i += TPB)
        out[i] = lds[i];
}

// ---------------------------------------------------------------------------
// Node kernel: sum partials per node, loss terms, block-reduce, 1 atomic/block.
// ---------------------------------------------------------------------------
__global__ void pf_node_kernel(const float* __restrict__ nf,
                               const float2* __restrict__ partial,
                               float* __restrict__ acc,
                               int n_nodes, int split) {
    int i = blockIdx.x * blockDim.x + threadIdx.x;
    float c = 0.0f;
    if (i < n_nodes) {
        float4 f = *reinterpret_cast<const float4*>(&nf[(size_t)i * 4]);
        float p = f.z, q = f.w;
        const float2* pp = partial + i;
        for (int s = 0; s < split; ++s) {
            float2 fl = pp[(size_t)s * n_nodes];
            p += fl.x;
            q += fl.y;
        }
        float vmag = sqrtf(f.x * f.x + f.y * f.y);
        float lv = fmaxf(V_LO - vmag, 0.0f);
        float uv = fmaxf(vmag - V_HI, 0.0f);
        c = p * p + q * q + lv * lv + uv * uv;
    }
    #pragma unroll
    for (int off = 32; off > 0; off >>= 1)
        c += __shfl_down(c, off);
    __shared__ float wsum[4];
    int lane = threadIdx.x & 63;
    int wid  = threadIdx.x >> 6;
    if (lane == 0) wsum[wid] = c;
    __syncthreads();
    if (threadIdx.x == 0) {
        float s = 0.0f;
        int nw = blockDim.x >> 6;
        for (int w = 0; w < nw; ++w) s += wsum[w];
        atomicAdd(acc, s);
    }
}

__global__ void pf_finalize_kernel(const float* __restrict__ acc,
                                   float* __restrict__ out,
                                   float inv_n) {
    out[0] = acc[0] * inv_n;
}

extern "C" void kernel_launch(void* const* d_in, const int* in_sizes, int n_in,
                              void* d_out, int out_size, void* d_ws, size_t ws_size,
                              hipStream_t stream) {
    const float* nf     = (const float*)d_in[0];    // (N,4) f32
    const int*   ei     = (const int*)d_in[1];      // (2,E) int
    const float* probs  = (const float*)d_in[2];    // (E,) f32
    const float* params = (const float* )d_in[3];   // (E,2) f32 flat

    int n_nodes = in_sizes[0] / 4;
    int n_edges = in_sizes[2];

    // ws layout: [acc (pad to 256B)][partial: split * n_nodes * float2]
    float*  acc     = (float*)d_ws;
    float2* partial = (float2*)((char*)d_ws + 256);

    size_t slot_bytes = (size_t)n_nodes * sizeof(float2);
    int split = (int)((ws_size - 256) / slot_bytes);
    if (split > MAX_SPLIT) split = MAX_SPLIT;
    if (split < 1) split = 1;

    int nbins = (n_nodes + BIN_ELEMS - 1) / BIN_ELEMS;
    int per_chunk = (n_edges + split - 1) / split;
    per_chunk = (per_chunk + 1) & ~1;               // even, so 2-edge loads never straddle

    size_t lds_bytes = (size_t)BIN_ELEMS * sizeof(float2);   // 160 KB
    hipFuncSetAttribute((const void*)pf_edge_scan,
                        hipFuncAttributeMaxDynamicSharedMemorySize,
                        (int)lds_bytes);

    // only acc needs zeroing: partial slices are fully overwritten
    hipMemsetAsync(d_ws, 0, 256, stream);

    pf_edge_scan<<<nbins * split, TPB, lds_bytes, stream>>>(
        nf, ei, probs, params, partial, n_edges, n_nodes, nbins, per_chunk);

    int nblocks = (n_nodes + 255) / 256;
    pf_node_kernel<<<nblocks, 256, 0, stream>>>(nf, partial, acc, n_nodes, split);

    pf_finalize_kernel<<<1, 1, 0, stream>>>(acc, (float*)d_out,
                                            1.0f / (float)n_nodes);
}